// Round 6
// baseline (715.207 us; speedup 1.0000x reference)
//
#include <hip/hip_runtime.h>

#define T_STEPS 1024
#define B_TOT   512
#define VOCAB   1000
#define EMB     64
#define HID     64
#define GATES   256   // 4*HID

typedef float f4 __attribute__((ext_vector_type(4)));
typedef float f2 __attribute__((ext_vector_type(2)));

__device__ __forceinline__ float fast_rcp(float x)  { return __builtin_amdgcn_rcpf(x); }
__device__ __forceinline__ float fast_exp2(float x) { return __builtin_amdgcn_exp2f(x); }

__device__ __forceinline__ float sigmoid_f(float x) {
    return fast_rcp(1.0f + fast_exp2(-1.4426950408889634f * x));
}
__device__ __forceinline__ float tanh_f(float x) {
    float e = fast_exp2(2.8853900817779268f * x);
    return 1.0f - 2.0f * fast_rcp(e + 1.0f);
}

// ---------------------------------------------------------------------------
// Kernel 1: zx table. Layout [dir][vocab][wave][unit][pair]:
//   thread j (0..255): p=j&1, u=(j>>1)&63, w=j>>7, source col=(2w+p)*64+u.
// Recurrent lane (w,u) gathers float2 index tok*128 + w*64 + u.
// ---------------------------------------------------------------------------
__global__ __launch_bounds__(256, 4)
void zx_table_kernel(const float* __restrict__ emb,
                     const float* __restrict__ Wx_f, const float* __restrict__ b_f,
                     const float* __restrict__ Wx_b, const float* __restrict__ b_b,
                     float* __restrict__ zx_tab)
{
    const int bid = blockIdx.x;            // 0..1999
    const int dir = bid / VOCAB;
    const int v   = bid - dir * VOCAB;
    const int j   = threadIdx.x;
    const int p   = j & 1;
    const int u   = (j >> 1) & 63;
    const int w   = j >> 7;
    const int col = (2 * w + p) * HID + u;

    const float* __restrict__ Wx = dir ? Wx_b : Wx_f;
    const float* __restrict__ bv = dir ? b_b  : b_f;

    __shared__ float4 x4[EMB / 4];
    if (j < EMB / 4) x4[j] = ((const float4*)emb)[v * (EMB / 4) + j];
    __syncthreads();

    float a0 = bv[col], a1 = 0.f, a2 = 0.f, a3 = 0.f;
#pragma unroll
    for (int q = 0; q < EMB / 4; ++q) {
        float4 xv = x4[q];
        a0 = fmaf(xv.x, Wx[(4 * q + 0) * GATES + col], a0);
        a1 = fmaf(xv.y, Wx[(4 * q + 1) * GATES + col], a1);
        a2 = fmaf(xv.z, Wx[(4 * q + 2) * GATES + col], a2);
        a3 = fmaf(xv.w, Wx[(4 * q + 3) * GATES + col], a3);
    }
    zx_tab[(dir * VOCAB + v) * GATES + j] = (a0 + a1) + (a2 + a3);
}

// ---------------------------------------------------------------------------
// Kernel 2: recurrence, all fp32, ONE barrier per step.
// Block = 128 thr = 2 waves per (dir,row). Wave 0 lane u: gates i,f of unit
// u; wave 1: gates g,o. After the dots each wave activates its own 2 gates,
// publishes them (parity double-buffered), barrier, then BOTH waves
// redundantly compute the c/h update (identical fp32 values) and BOTH write
// hbuf — so each wave's next-step hbuf reads are ordered after its own
// write and no second barrier is needed.
// amdgpu_waves_per_eu(2,2): occupancy is grid-capped at 2 waves/SIMD anyway;
// pinning it gives the allocator the full 256-VGPR budget so the 128
// register-resident weights stay in arch VGPRs (no v_accvgpr copies).
// ---------------------------------------------------------------------------
__global__ __launch_bounds__(128) __attribute__((amdgpu_waves_per_eu(2, 2)))
void lstm_rec_kernel(const int* __restrict__ tokens,
                     const float* __restrict__ Wh_f,
                     const float* __restrict__ Wh_b,
                     const float* __restrict__ zx_tab,
                     float* __restrict__ out)
{
    const int bx  = blockIdx.x;        // 0..1023
    const int dir = bx >> 9;
    const int row = bx & 511;
    const int u   = threadIdx.x & 63;  // hidden unit
    const int w   = threadIdx.x >> 6;  // wave id: 0 -> i,f ; 1 -> g,o

    const float* __restrict__ Wh   = dir ? Wh_b : Wh_f;
    const f2*    __restrict__ zx2  = (const f2*)(zx_tab + dir * (VOCAB * GATES));
    const int*   __restrict__ trow = tokens + row * T_STEPS;

    // 128 register-resident fp32 weights: columns (2w)*64+u and (2w+1)*64+u.
    const int colA = (2 * w) * HID + u;
    const int colB = colA + HID;
    float whA[HID], whB[HID];
#pragma unroll
    for (int k = 0; k < HID; ++k) whA[k] = Wh[k * GATES + colA];
#pragma unroll
    for (int k = 0; k < HID; ++k) whB[k] = Wh[k * GATES + colB];

    __shared__ float hbuf[HID];          // h (both waves write identical bits)
    __shared__ float sA[2][2][HID];      // [parity][w][u]: act of gate 2w
    __shared__ float sB[2][2][HID];      // [parity][w][u]: act of gate 2w+1

    if (threadIdx.x < HID) hbuf[threadIdx.x] = 0.0f;
    float c    = 0.0f;
    float hval = 0.0f;
    int   p    = 0;                      // parity (uniform)
    __syncthreads();

    // wave-uniform token chain + zx prefetch (float2 per lane)
    int tokc = trow[dir ? (T_STEPS - 1) : 0];
    int tokn = trow[dir ? (T_STEPS - 2) : 1];
    f2  zxc  = zx2[tokc * 128 + w * 64 + u];

    const f4* __restrict__ hb4 = (const f4*)hbuf;

#pragma unroll 1
    for (int t = 0; t < T_STEPS; ++t) {
        // prefetches first: latency hides under the fmac block
        int t2   = (t + 2 < T_STEPS) ? (t + 2) : (T_STEPS - 1);
        int tokf = trow[dir ? (T_STEPS - 1 - t2) : t2];
        f2  zxn  = zx2[tokn * 128 + w * 64 + u];

        if (tokc != 0) {                 // uniform; masked steps carry state
            // ---- two 64-dim dots, 8 independent fmac chains ----
            float aA0 = zxc.x, aA1 = 0.f, aA2 = 0.f, aA3 = 0.f;
            float aB0 = zxc.y, aB1 = 0.f, aB2 = 0.f, aB3 = 0.f;
#pragma unroll
            for (int q = 0; q < HID / 4; ++q) {
                f4 hv = hb4[q];          // LDS broadcast, conflict-free
                aA0 = fmaf(hv.x, whA[4 * q + 0], aA0);
                aA1 = fmaf(hv.y, whA[4 * q + 1], aA1);
                aA2 = fmaf(hv.z, whA[4 * q + 2], aA2);
                aA3 = fmaf(hv.w, whA[4 * q + 3], aA3);
                aB0 = fmaf(hv.x, whB[4 * q + 0], aB0);
                aB1 = fmaf(hv.y, whB[4 * q + 1], aB1);
                aB2 = fmaf(hv.z, whB[4 * q + 2], aB2);
                aB3 = fmaf(hv.w, whB[4 * q + 3], aB3);
            }
            float zA = (aA0 + aA1) + (aA2 + aA3);
            float zB = (aB0 + aB1) + (aB2 + aB3);

            // ---- own-gate activations (all 128 lanes busy) ----
            float actA = w ? tanh_f(zA) : sigmoid_f(zA);   // g : i
            float actB = sigmoid_f(zB);                    // o : f
            sA[p][w][u] = actA;
            sB[p][w][u] = actB;
            __syncthreads();             // the ONLY barrier per step

            // ---- redundant lane-parallel update on both waves ----
            float oA = sA[p][w ^ 1][u];
            float oB = sB[p][w ^ 1][u];
            float ig = w ? oA   : actA;
            float fg = w ? oB   : actB;
            float gg = w ? actA : oA;
            float og = w ? actB : oB;
            c    = fmaf(fg, c, ig * gg);
            hval = og * tanh_f(c);
            hbuf[u] = hval;              // identical bits from both waves
            p ^= 1;
        }

        tokc = tokn; tokn = tokf; zxc = zxn;
    }

    if (w == 0)
        out[row * (2 * HID) + dir * HID + u] = hval;
}

extern "C" void kernel_launch(void* const* d_in, const int* in_sizes, int n_in,
                              void* d_out, int out_size, void* d_ws, size_t ws_size,
                              hipStream_t stream) {
    const int*   tokens = (const int*)  d_in[0];
    const float* emb    = (const float*)d_in[1];
    const float* Wx_f   = (const float*)d_in[2];
    const float* Wh_f   = (const float*)d_in[3];
    const float* b_f    = (const float*)d_in[4];
    const float* Wx_b   = (const float*)d_in[5];
    const float* Wh_b   = (const float*)d_in[6];
    const float* b_b    = (const float*)d_in[7];
    float* out = (float*)d_out;

    float* zx_tab = (float*)d_ws;   // 2*1000*256*4 = 1.95 MB of d_ws

    hipLaunchKernelGGL(zx_table_kernel, dim3(2 * VOCAB), dim3(GATES), 0, stream,
                       emb, Wx_f, b_f, Wx_b, b_b, zx_tab);
    hipLaunchKernelGGL(lstm_rec_kernel, dim3(2 * B_TOT), dim3(128), 0, stream,
                       tokens, Wh_f, Wh_b, zx_tab, out);
}

// Round 7
// 681.199 us; speedup vs baseline: 1.0499x; 1.0499x over previous
//
#include <hip/hip_runtime.h>

#define T_STEPS 1024
#define B_TOT   512
#define VOCAB   1000
#define EMB     64
#define HID     64
#define GATES   256   // 4*HID

typedef float f4 __attribute__((ext_vector_type(4)));
typedef float f2 __attribute__((ext_vector_type(2)));

__device__ __forceinline__ float fast_rcp(float x)  { return __builtin_amdgcn_rcpf(x); }
__device__ __forceinline__ float fast_exp2(float x) { return __builtin_amdgcn_exp2f(x); }

__device__ __forceinline__ float sigmoid_f(float x) {
    return fast_rcp(1.0f + fast_exp2(-1.4426950408889634f * x));
}
__device__ __forceinline__ float tanh_f(float x) {
    float e = fast_exp2(2.8853900817779268f * x);
    return 1.0f - 2.0f * fast_rcp(e + 1.0f);
}

// Arch-VGPR-pinned FMA: "v" constraints force acc, a, b into arch VGPRs, so
// the register allocator cannot demote the weight arrays to AGPRs (which
// would cost a v_accvgpr_read per use). Non-volatile: scheduler may reorder.
__device__ __forceinline__ void fmac_v(float& acc, float a, float b) {
    asm("v_fmac_f32 %0, %1, %2" : "+v"(acc) : "v"(a), "v"(b));
}

// ---------------------------------------------------------------------------
// Kernel 1: zx table. Layout [dir][vocab][wave][unit][pair]:
//   thread j (0..255): p=j&1, u=(j>>1)&63, w=j>>7, source col=(2w+p)*64+u.
// Recurrent lane (w,u) gathers float2 index tok*128 + w*64 + u.
// ---------------------------------------------------------------------------
__global__ __launch_bounds__(256, 4)
void zx_table_kernel(const float* __restrict__ emb,
                     const float* __restrict__ Wx_f, const float* __restrict__ b_f,
                     const float* __restrict__ Wx_b, const float* __restrict__ b_b,
                     float* __restrict__ zx_tab)
{
    const int bid = blockIdx.x;            // 0..1999
    const int dir = bid / VOCAB;
    const int v   = bid - dir * VOCAB;
    const int j   = threadIdx.x;
    const int p   = j & 1;
    const int u   = (j >> 1) & 63;
    const int w   = j >> 7;
    const int col = (2 * w + p) * HID + u;

    const float* __restrict__ Wx = dir ? Wx_b : Wx_f;
    const float* __restrict__ bv = dir ? b_b  : b_f;

    __shared__ float4 x4[EMB / 4];
    if (j < EMB / 4) x4[j] = ((const float4*)emb)[v * (EMB / 4) + j];
    __syncthreads();

    float a0 = bv[col], a1 = 0.f, a2 = 0.f, a3 = 0.f;
#pragma unroll
    for (int q = 0; q < EMB / 4; ++q) {
        float4 xv = x4[q];
        a0 = fmaf(xv.x, Wx[(4 * q + 0) * GATES + col], a0);
        a1 = fmaf(xv.y, Wx[(4 * q + 1) * GATES + col], a1);
        a2 = fmaf(xv.z, Wx[(4 * q + 2) * GATES + col], a2);
        a3 = fmaf(xv.w, Wx[(4 * q + 3) * GATES + col], a3);
    }
    zx_tab[(dir * VOCAB + v) * GATES + j] = (a0 + a1) + (a2 + a3);
}

// ---------------------------------------------------------------------------
// Kernel 2: recurrence, all fp32 — R4 structure exactly (best so far), with
// the dot-product FMAs pinned to arch VGPRs via inline asm.
// Block = 128 thr = 2 waves per (dir,row): 1024 blocks -> 2 waves/SIMD.
//   wave 0, lane u: gates i,f of unit u ; wave 1, lane u: gates g,o.
// Per step: 128 asm fmac/lane (8 chains) -> own-gate activations ->
// wave1 writes float2{g,o} -> barrier -> wave0 lane-parallel c/h update,
// writes h -> barrier.
// ---------------------------------------------------------------------------
__global__ __launch_bounds__(128, 2)
void lstm_rec_kernel(const int* __restrict__ tokens,
                     const float* __restrict__ Wh_f,
                     const float* __restrict__ Wh_b,
                     const float* __restrict__ zx_tab,
                     float* __restrict__ out)
{
    const int bx  = blockIdx.x;        // 0..1023
    const int dir = bx >> 9;
    const int row = bx & 511;
    const int u   = threadIdx.x & 63;  // hidden unit
    const int w   = threadIdx.x >> 6;  // wave id: 0 -> gates i,f ; 1 -> g,o

    const float* __restrict__ Wh   = dir ? Wh_b : Wh_f;
    const f2*    __restrict__ zx2  = (const f2*)(zx_tab + dir * (VOCAB * GATES));
    const int*   __restrict__ trow = tokens + row * T_STEPS;

    // 128 register-resident fp32 weights: columns (2w)*64+u and (2w+1)*64+u.
    const int colA = (2 * w) * HID + u;
    const int colB = colA + HID;
    float whA[HID], whB[HID];
#pragma unroll
    for (int k = 0; k < HID; ++k) whA[k] = Wh[k * GATES + colA];
#pragma unroll
    for (int k = 0; k < HID; ++k) whB[k] = Wh[k * GATES + colB];

    __shared__ float hbuf[HID];        // h broadcast (fp32)
    __shared__ f2    act2[HID];        // wave1 -> wave0: {g, o}

    if (threadIdx.x < HID) hbuf[threadIdx.x] = 0.0f;
    float c = 0.0f;                    // cell state (wave 0 lanes)
    __syncthreads();

    // wave-uniform token chain + zx prefetch (float2 per lane)
    int tokc = trow[dir ? (T_STEPS - 1) : 0];
    int tokn = trow[dir ? (T_STEPS - 2) : 1];
    f2  zxc  = zx2[tokc * 128 + w * 64 + u];

    const f4* __restrict__ hb4 = (const f4*)hbuf;

#pragma unroll 1
    for (int t = 0; t < T_STEPS; ++t) {
        // prefetches first: latency hides under the fmac block
        int t2   = (t + 2 < T_STEPS) ? (t + 2) : (T_STEPS - 1);
        int tokf = trow[dir ? (T_STEPS - 1 - t2) : t2];
        f2  zxn  = zx2[tokn * 128 + w * 64 + u];

        // ---- two 64-dim dots, 8 independent asm-fmac chains ----
        float aA0 = zxc.x, aA1 = 0.f, aA2 = 0.f, aA3 = 0.f;
        float aB0 = zxc.y, aB1 = 0.f, aB2 = 0.f, aB3 = 0.f;
#pragma unroll
        for (int q = 0; q < HID / 4; ++q) {
            f4 hv = hb4[q];                       // LDS broadcast, conflict-free
            fmac_v(aA0, hv.x, whA[4 * q + 0]);
            fmac_v(aA1, hv.y, whA[4 * q + 1]);
            fmac_v(aA2, hv.z, whA[4 * q + 2]);
            fmac_v(aA3, hv.w, whA[4 * q + 3]);
            fmac_v(aB0, hv.x, whB[4 * q + 0]);
            fmac_v(aB1, hv.y, whB[4 * q + 1]);
            fmac_v(aB2, hv.z, whB[4 * q + 2]);
            fmac_v(aB3, hv.w, whB[4 * q + 3]);
        }
        float zA = (aA0 + aA1) + (aA2 + aA3);
        float zB = (aB0 + aB1) + (aB2 + aB3);

        // ---- own-gate activations (both waves busy, wave-uniform branch) ----
        float actA, actB;
        if (w == 0) {                  // i, f
            actA = sigmoid_f(zA);
            actB = sigmoid_f(zB);
        } else {                       // g, o
            actA = tanh_f(zA);
            actB = sigmoid_f(zB);
            f2 go; go.x = actA; go.y = actB;
            act2[u] = go;
        }
        __syncthreads();

        // ---- state update: wave 0, lane-parallel ----
        if (w == 0 && tokc != 0) {     // Keras mask_zero: carry when padded
            f2 go = act2[u];
            c = fmaf(actB, c, actA * go.x);        // c = f*c + i*g
            hbuf[u] = go.y * tanh_f(c);            // h = o*tanh(c)
        }
        __syncthreads();

        tokc = tokn; tokn = tokf; zxc = zxn;
    }

    if (w == 0)
        out[row * (2 * HID) + dir * HID + u] = hbuf[u];
}

extern "C" void kernel_launch(void* const* d_in, const int* in_sizes, int n_in,
                              void* d_out, int out_size, void* d_ws, size_t ws_size,
                              hipStream_t stream) {
    const int*   tokens = (const int*)  d_in[0];
    const float* emb    = (const float*)d_in[1];
    const float* Wx_f   = (const float*)d_in[2];
    const float* Wh_f   = (const float*)d_in[3];
    const float* b_f    = (const float*)d_in[4];
    const float* Wx_b   = (const float*)d_in[5];
    const float* Wh_b   = (const float*)d_in[6];
    const float* b_b    = (const float*)d_in[7];
    float* out = (float*)d_out;

    float* zx_tab = (float*)d_ws;   // 2*1000*256*4 = 1.95 MB of d_ws

    hipLaunchKernelGGL(zx_table_kernel, dim3(2 * VOCAB), dim3(GATES), 0, stream,
                       emb, Wx_f, b_f, Wx_b, b_b, zx_tab);
    hipLaunchKernelGGL(lstm_rec_kernel, dim3(2 * B_TOT), dim3(128), 0, stream,
                       tokens, Wh_f, Wh_b, zx_tab, out);
}

// Round 8
// 624.583 us; speedup vs baseline: 1.1451x; 1.0906x over previous
//
#include <hip/hip_runtime.h>

#define T_STEPS 1024
#define B_TOT   512
#define VOCAB   1000
#define EMB     64
#define HID     64
#define GATES   256   // 4*HID

typedef float f4 __attribute__((ext_vector_type(4)));
typedef float f2 __attribute__((ext_vector_type(2)));

__device__ __forceinline__ float fast_rcp(float x)  { return __builtin_amdgcn_rcpf(x); }
__device__ __forceinline__ float fast_exp2(float x) { return __builtin_amdgcn_exp2f(x); }

__device__ __forceinline__ float sigmoid_f(float x) {
    return fast_rcp(1.0f + fast_exp2(-1.4426950408889634f * x));
}
__device__ __forceinline__ float tanh_f(float x) {
    float e = fast_exp2(2.8853900817779268f * x);
    return 1.0f - 2.0f * fast_rcp(e + 1.0f);
}

// ---------------------------------------------------------------------------
// Kernel 1: zx table. Layout [dir][vocab][wave][unit][pair]:
//   thread j (0..255): p=j&1, u=(j>>1)&63, w=j>>7, source col=(2w+p)*64+u.
// Recurrent lane (w,u) gathers float2 index tok*128 + w*64 + u.
// ---------------------------------------------------------------------------
__global__ __launch_bounds__(256, 4)
void zx_table_kernel(const float* __restrict__ emb,
                     const float* __restrict__ Wx_f, const float* __restrict__ b_f,
                     const float* __restrict__ Wx_b, const float* __restrict__ b_b,
                     float* __restrict__ zx_tab)
{
    const int bid = blockIdx.x;            // 0..1999
    const int dir = bid / VOCAB;
    const int v   = bid - dir * VOCAB;
    const int j   = threadIdx.x;
    const int p   = j & 1;
    const int u   = (j >> 1) & 63;
    const int w   = j >> 7;
    const int col = (2 * w + p) * HID + u;

    const float* __restrict__ Wx = dir ? Wx_b : Wx_f;
    const float* __restrict__ bv = dir ? b_b  : b_f;

    __shared__ float4 x4[EMB / 4];
    if (j < EMB / 4) x4[j] = ((const float4*)emb)[v * (EMB / 4) + j];
    __syncthreads();

    float a0 = bv[col], a1 = 0.f, a2 = 0.f, a3 = 0.f;
#pragma unroll
    for (int q = 0; q < EMB / 4; ++q) {
        float4 xv = x4[q];
        a0 = fmaf(xv.x, Wx[(4 * q + 0) * GATES + col], a0);
        a1 = fmaf(xv.y, Wx[(4 * q + 1) * GATES + col], a1);
        a2 = fmaf(xv.z, Wx[(4 * q + 2) * GATES + col], a2);
        a3 = fmaf(xv.w, Wx[(4 * q + 3) * GATES + col], a3);
    }
    zx_tab[(dir * VOCAB + v) * GATES + j] = (a0 + a1) + (a2 + a3);
}

// ---------------------------------------------------------------------------
// Kernel 2: recurrence, all fp32 — R4 structure EXACTLY (best: 626 us).
// Single experimental variable vs R4: occupancy attribute is now
// __launch_bounds__(128) + amdgpu_waves_per_eu(1). Min-occupancy 1 lifts the
// allocator's VGPR budget (R4/R6's budget ~80 demoted the 128 weight values
// to AGPRs -> one v_accvgpr_read per FMA ≈ 256 extra cyc/wave-step). With
// usage ~200 regs the unified file (2048/SIMD) still fits 2 waves/SIMD at
// runtime, so the grid's 2 blocks/SIMD co-scheduling is preserved.
//   wave 0, lane u: gates i,f of unit u ; wave 1, lane u: gates g,o.
// Per step: 128 fmaf/lane (8 chains) -> own-gate activations ->
// wave1 writes float2{g,o} -> barrier -> wave0 lane-parallel c/h update,
// writes h -> barrier.
// ---------------------------------------------------------------------------
__global__ __launch_bounds__(128) __attribute__((amdgpu_waves_per_eu(1)))
void lstm_rec_kernel(const int* __restrict__ tokens,
                     const float* __restrict__ Wh_f,
                     const float* __restrict__ Wh_b,
                     const float* __restrict__ zx_tab,
                     float* __restrict__ out)
{
    const int bx  = blockIdx.x;        // 0..1023
    const int dir = bx >> 9;
    const int row = bx & 511;
    const int u   = threadIdx.x & 63;  // hidden unit
    const int w   = threadIdx.x >> 6;  // wave id: 0 -> gates i,f ; 1 -> g,o

    const float* __restrict__ Wh   = dir ? Wh_b : Wh_f;
    const f2*    __restrict__ zx2  = (const f2*)(zx_tab + dir * (VOCAB * GATES));
    const int*   __restrict__ trow = tokens + row * T_STEPS;

    // 128 register-resident fp32 weights: columns (2w)*64+u and (2w+1)*64+u.
    const int colA = (2 * w) * HID + u;
    const int colB = colA + HID;
    float whA[HID], whB[HID];
#pragma unroll
    for (int k = 0; k < HID; ++k) whA[k] = Wh[k * GATES + colA];
#pragma unroll
    for (int k = 0; k < HID; ++k) whB[k] = Wh[k * GATES + colB];

    __shared__ float hbuf[HID];        // h broadcast (fp32)
    __shared__ f2    act2[HID];        // wave1 -> wave0: {g, o}

    if (threadIdx.x < HID) hbuf[threadIdx.x] = 0.0f;
    float c = 0.0f;                    // cell state (wave 0 lanes)
    __syncthreads();

    // wave-uniform token chain + zx prefetch (float2 per lane)
    int tokc = trow[dir ? (T_STEPS - 1) : 0];
    int tokn = trow[dir ? (T_STEPS - 2) : 1];
    f2  zxc  = zx2[tokc * 128 + w * 64 + u];

    const f4* __restrict__ hb4 = (const f4*)hbuf;

#pragma unroll 1
    for (int t = 0; t < T_STEPS; ++t) {
        // prefetches first: latency hides under the fmac block
        int t2   = (t + 2 < T_STEPS) ? (t + 2) : (T_STEPS - 1);
        int tokf = trow[dir ? (T_STEPS - 1 - t2) : t2];
        f2  zxn  = zx2[tokn * 128 + w * 64 + u];

        // ---- two 64-dim dots, 8 independent fmac chains ----
        float aA0 = zxc.x, aA1 = 0.f, aA2 = 0.f, aA3 = 0.f;
        float aB0 = zxc.y, aB1 = 0.f, aB2 = 0.f, aB3 = 0.f;
#pragma unroll
        for (int q = 0; q < HID / 4; ++q) {
            f4 hv = hb4[q];                       // LDS broadcast, conflict-free
            aA0 = fmaf(hv.x, whA[4 * q + 0], aA0);
            aA1 = fmaf(hv.y, whA[4 * q + 1], aA1);
            aA2 = fmaf(hv.z, whA[4 * q + 2], aA2);
            aA3 = fmaf(hv.w, whA[4 * q + 3], aA3);
            aB0 = fmaf(hv.x, whB[4 * q + 0], aB0);
            aB1 = fmaf(hv.y, whB[4 * q + 1], aB1);
            aB2 = fmaf(hv.z, whB[4 * q + 2], aB2);
            aB3 = fmaf(hv.w, whB[4 * q + 3], aB3);
        }
        float zA = (aA0 + aA1) + (aA2 + aA3);
        float zB = (aB0 + aB1) + (aB2 + aB3);

        // ---- own-gate activations (both waves busy, wave-uniform branch) ----
        float actA, actB;
        if (w == 0) {                  // i, f
            actA = sigmoid_f(zA);
            actB = sigmoid_f(zB);
        } else {                       // g, o
            actA = tanh_f(zA);
            actB = sigmoid_f(zB);
            f2 go; go.x = actA; go.y = actB;
            act2[u] = go;
        }
        __syncthreads();

        // ---- state update: wave 0, lane-parallel ----
        if (w == 0 && tokc != 0) {     // Keras mask_zero: carry when padded
            f2 go = act2[u];
            c = fmaf(actB, c, actA * go.x);        // c = f*c + i*g
            hbuf[u] = go.y * tanh_f(c);            // h = o*tanh(c)
        }
        __syncthreads();

        tokc = tokn; tokn = tokf; zxc = zxn;
    }

    if (w == 0)
        out[row * (2 * HID) + dir * HID + u] = hbuf[u];
}

extern "C" void kernel_launch(void* const* d_in, const int* in_sizes, int n_in,
                              void* d_out, int out_size, void* d_ws, size_t ws_size,
                              hipStream_t stream) {
    const int*   tokens = (const int*)  d_in[0];
    const float* emb    = (const float*)d_in[1];
    const float* Wx_f   = (const float*)d_in[2];
    const float* Wh_f   = (const float*)d_in[3];
    const float* b_f    = (const float*)d_in[4];
    const float* Wx_b   = (const float*)d_in[5];
    const float* Wh_b   = (const float*)d_in[6];
    const float* b_b    = (const float*)d_in[7];
    float* out = (float*)d_out;

    float* zx_tab = (float*)d_ws;   // 2*1000*256*4 = 1.95 MB of d_ws

    hipLaunchKernelGGL(zx_table_kernel, dim3(2 * VOCAB), dim3(GATES), 0, stream,
                       emb, Wx_f, b_f, Wx_b, b_b, zx_tab);
    hipLaunchKernelGGL(lstm_rec_kernel, dim3(2 * B_TOT), dim3(128), 0, stream,
                       tokens, Wh_f, Wh_b, zx_tab, out);
}